// Round 4
// baseline (347.208 us; speedup 1.0000x reference)
//
#include <hip/hip_runtime.h>

#define N 16384
#define IN_F 128
#define OUT_F 32
#define NSPLIT 8            // k-splits in the aggregate kernel
#define KR (N / NSPLIT)     // 2048 k per WG
#define KC 64               // k per chunk
#define CHUNKS (KR / KC)    // 32
// Per stage: adj tile 64r x 64k = 16KB (4 gload_lds/thread), supT 32j x 64k = 8KB (2)

#define GLOAD_LDS16(g, l) \
    __builtin_amdgcn_global_load_lds((const __attribute__((address_space(1))) void*)(g), \
                                     (__attribute__((address_space(3))) void*)(l), 16, 0, 0)

// Kernel A: supT[j][i] = sum_k input[i][k] * weight[k][j]   (transposed support)
__global__ __launch_bounds__(256) void gcn_support(const float* __restrict__ inp,
                                                   const float* __restrict__ w,
                                                   float* __restrict__ supT) {
    __shared__ float wl[IN_F * OUT_F];  // 16 KB
    int tid = threadIdx.x;
#pragma unroll
    for (int u = 0; u < 4; ++u) {
        int idx = (u * 256 + tid) * 4;
        *(float4*)&wl[idx] = *(const float4*)&w[idx];
    }
    __syncthreads();

    int gid = blockIdx.x * 256 + tid;
    int i  = gid >> 2;   // row 0..16383
    int ks = gid & 3;    // k quarter

    float acc[OUT_F];
#pragma unroll
    for (int j = 0; j < OUT_F; ++j) acc[j] = 0.f;

    const float* ip = inp + (size_t)i * IN_F + ks * 32;
#pragma unroll
    for (int kb = 0; kb < 8; ++kb) {
        float4 a4 = *(const float4*)(ip + kb * 4);
        float av[4] = {a4.x, a4.y, a4.z, a4.w};
#pragma unroll
        for (int kk = 0; kk < 4; ++kk) {
            int k = ks * 32 + kb * 4 + kk;
            const float* wr = &wl[k * OUT_F];
#pragma unroll
            for (int j4 = 0; j4 < 8; ++j4) {
                float4 w4 = *(const float4*)(wr + j4 * 4);
                acc[j4 * 4 + 0] = fmaf(av[kk], w4.x, acc[j4 * 4 + 0]);
                acc[j4 * 4 + 1] = fmaf(av[kk], w4.y, acc[j4 * 4 + 1]);
                acc[j4 * 4 + 2] = fmaf(av[kk], w4.z, acc[j4 * 4 + 2]);
                acc[j4 * 4 + 3] = fmaf(av[kk], w4.w, acc[j4 * 4 + 3]);
            }
        }
    }
#pragma unroll
    for (int j = 0; j < OUT_F; ++j) {
        acc[j] += __shfl_xor(acc[j], 1);
        acc[j] += __shfl_xor(acc[j], 2);
    }
#pragma unroll
    for (int jj = 0; jj < 8; ++jj) {
        int j = ks * 8 + jj;
        supT[(size_t)j * N + i] = acc[j];
    }
}

// Kernel B: out[row][j] += sum_{k in split} adj[row][k] * supT[j][k]
// Both operands staged via global_load_lds, double-buffered, counted vmcnt(6)
// so 6 DMA loads stay in flight across the compute phase (never drained in-loop).
// Wave = jh(2) x rg(4) x kl(8). Thread: 4 rows x 16 cols (64 acc regs).
__global__ __launch_bounds__(256, 3) void gcn_aggregate(const float* __restrict__ adj,
                                                        const float* __restrict__ supT,
                                                        float* __restrict__ out) {
    __shared__ float sA[2][64 * KC];     // adj tiles,  2 x 16 KB, [row][k]
    __shared__ float sB[2][OUT_F * KC];  // supT tiles, 2 x  8 KB, [j][k]

    int wg = blockIdx.x;
    int rb = wg >> 3;          // row block 0..255 (64 rows each)
    int sp = wg & 7;           // k split
    int tid  = threadIdx.x;
    int wv   = tid >> 6;
    int lane = tid & 63;
    int jh = lane >> 5;        // j half (bit 5)
    int rg = (lane >> 3) & 3;  // row group (bits 3-4)
    int kl = lane & 7;         // k lane (bits 0-2)

    int rowblk = rb * 64;
    int kbase  = sp * KR;

    float acc[4][16];
#pragma unroll
    for (int r = 0; r < 4; ++r)
#pragma unroll
        for (int j = 0; j < 16; ++j) acc[r][j] = 0.f;

    // Stage chunk c into buffer buf: 6 global_load_lds per thread.
    // LDS dest is wave-uniform base; HW writes base + lane*16B, so slot f
    // (= u*256 + tid) maps linearly over [row][k4] row-major.
    auto stage = [&](int buf, int c) {
#pragma unroll
        for (int u = 0; u < 4; ++u) {        // adj: 1024 float4 slots
            int f   = u * 256 + tid;
            int row = f >> 4;                // 16 float4 per row (KC=64)
            int k4  = f & 15;
            const float* gp = adj + (size_t)(rowblk + row) * N + kbase + c * KC + k4 * 4;
            float* lp = &sA[buf][(u * 256 + wv * 64) * 4];
            GLOAD_LDS16(gp, lp);
        }
#pragma unroll
        for (int u = 0; u < 2; ++u) {        // supT: 512 float4 slots
            int f  = u * 256 + tid;
            int j  = f >> 4;
            int k4 = f & 15;
            const float* gp = supT + (size_t)j * N + kbase + c * KC + k4 * 4;
            float* lp = &sB[buf][(u * 256 + wv * 64) * 4];
            GLOAD_LDS16(gp, lp);
        }
    };

    stage(0, 0);

    for (int c = 0; c < CHUNKS; ++c) {
        int cur = c & 1;
        // all waves finished reading buf cur^1 (previous compute) before we overwrite it
        __builtin_amdgcn_s_barrier();
        if (c + 1 < CHUNKS) {
            stage(cur ^ 1, c + 1);
            asm volatile("s_waitcnt vmcnt(6)" ::: "memory");  // chunk c's 6 landed; c+1's stay in flight
        } else {
            asm volatile("s_waitcnt vmcnt(0)" ::: "memory");
        }
        __builtin_amdgcn_sched_barrier(0);
        __builtin_amdgcn_s_barrier();        // chunk c visible to all waves

        const float* Ab = &sA[cur][(wv * 16 + rg * 4) * KC + kl * 4];
        const float* Bb = &sB[cur][(jh * 16) * KC + kl * 4];
#pragma unroll
        for (int it = 0; it < KC / 32; ++it) {
            float4 a0 = *(const float4*)(Ab + 0 * KC + it * 32);
            float4 a1 = *(const float4*)(Ab + 1 * KC + it * 32);
            float4 a2 = *(const float4*)(Ab + 2 * KC + it * 32);
            float4 a3 = *(const float4*)(Ab + 3 * KC + it * 32);
#pragma unroll
            for (int jj = 0; jj < 16; ++jj) {
                float4 b4 = *(const float4*)(Bb + jj * KC + it * 32);
                acc[0][jj] = fmaf(a0.x, b4.x, fmaf(a0.y, b4.y, fmaf(a0.z, b4.z, fmaf(a0.w, b4.w, acc[0][jj]))));
                acc[1][jj] = fmaf(a1.x, b4.x, fmaf(a1.y, b4.y, fmaf(a1.z, b4.z, fmaf(a1.w, b4.w, acc[1][jj]))));
                acc[2][jj] = fmaf(a2.x, b4.x, fmaf(a2.y, b4.y, fmaf(a2.z, b4.z, fmaf(a2.w, b4.w, acc[2][jj]))));
                acc[3][jj] = fmaf(a3.x, b4.x, fmaf(a3.y, b4.y, fmaf(a3.z, b4.z, fmaf(a3.w, b4.w, acc[3][jj]))));
            }
        }
    }

    // Reduce-scatter across the 8 k-lanes (masks 4,2,1). All register indices
    // compile-time; runtime half-selection via cndmask.
    float r1[4][8];
#pragma unroll
    for (int r = 0; r < 4; ++r)
#pragma unroll
        for (int i = 0; i < 8; ++i) {
            bool hi = (kl & 4) != 0;
            float keep = hi ? acc[r][8 + i] : acc[r][i];
            float send = hi ? acc[r][i] : acc[r][8 + i];
            r1[r][i] = keep + __shfl_xor(send, 4);
        }
    float r2[4][4];
#pragma unroll
    for (int r = 0; r < 4; ++r)
#pragma unroll
        for (int i = 0; i < 4; ++i) {
            bool hi = (kl & 2) != 0;
            float keep = hi ? r1[r][4 + i] : r1[r][i];
            float send = hi ? r1[r][i] : r1[r][4 + i];
            r2[r][i] = keep + __shfl_xor(send, 2);
        }
    float r3[4][2];
#pragma unroll
    for (int r = 0; r < 4; ++r)
#pragma unroll
        for (int i = 0; i < 2; ++i) {
            bool hi = (kl & 1) != 0;
            float keep = hi ? r2[r][2 + i] : r2[r][i];
            float send = hi ? r2[r][i] : r2[r][2 + i];
            r3[r][i] = keep + __shfl_xor(send, 1);
        }

    // lane (jh,rg,kl) holds cols j = jh*16 + 2*kl + {0,1} for its 4 rows
#pragma unroll
    for (int r = 0; r < 4; ++r) {
        int row = rowblk + wv * 16 + rg * 4 + r;
        int j   = jh * 16 + 2 * kl;
        atomicAdd(&out[row * 32 + j + 0], r3[r][0]);
        atomicAdd(&out[row * 32 + j + 1], r3[r][1]);
    }
}

__global__ __launch_bounds__(256) void gcn_relu(float* __restrict__ out) {
    int gid = blockIdx.x * 256 + threadIdx.x;  // 131072 float4s
    float4* p = (float4*)out;
    float4 v = p[gid];
    v.x = fmaxf(v.x, 0.f);
    v.y = fmaxf(v.y, 0.f);
    v.z = fmaxf(v.z, 0.f);
    v.w = fmaxf(v.w, 0.f);
    p[gid] = v;
}

extern "C" void kernel_launch(void* const* d_in, const int* in_sizes, int n_in,
                              void* d_out, int out_size, void* d_ws, size_t ws_size,
                              hipStream_t stream) {
    (void)in_sizes; (void)n_in; (void)out_size; (void)ws_size;
    const float* inp = (const float*)d_in[0];   // [16384,128]
    const float* adj = (const float*)d_in[1];   // [16384,16384]
    const float* wgt = (const float*)d_in[2];   // [128,32]
    float* out  = (float*)d_out;                // [16384,32]
    float* supT = (float*)d_ws;                 // [32,16384] = 2 MB scratch

    hipMemsetAsync(out, 0, (size_t)N * OUT_F * sizeof(float), stream);
    gcn_support<<<(N * 4) / 256, 256, 0, stream>>>(inp, wgt, supT);
    gcn_aggregate<<<(N / 64) * NSPLIT, 256, 0, stream>>>(adj, supT, out);
    gcn_relu<<<(N * OUT_F / 4) / 256, 256, 0, stream>>>(out);
}

// Round 5
// 251.353 us; speedup vs baseline: 1.3814x; 1.3814x over previous
//
#include <hip/hip_runtime.h>

#define N 16384
#define IN_F 128
#define OUT_F 32
#define NSPLIT 8            // k-splits in the aggregate kernel
#define KR (N / NSPLIT)     // 2048 k per WG
#define KC 128              // k per chunk
#define CHUNKS (KR / KC)    // 16
#define ROWS 32             // adj rows per WG

typedef __attribute__((ext_vector_type(8))) short short8v;
typedef __attribute__((ext_vector_type(4))) float float4v;

#define GLOAD_LDS16(g, l) \
    __builtin_amdgcn_global_load_lds((const __attribute__((address_space(1))) void*)(g), \
                                     (__attribute__((address_space(3))) void*)(l), 16, 0, 0)

// fp32 -> bf16 bits, round-to-nearest-even (finite inputs only)
__device__ __forceinline__ unsigned short f2bf(float x) {
    unsigned int u = __float_as_uint(x);
    u += 0x7FFFu + ((u >> 16) & 1u);
    return (unsigned short)(u >> 16);
}

// Kernel A: supB[j][i] = bf16( sum_k input[i][k] * weight[k][j] )  (transposed support, bf16)
__global__ __launch_bounds__(256) void gcn_support(const float* __restrict__ inp,
                                                   const float* __restrict__ w,
                                                   unsigned short* __restrict__ supB) {
    __shared__ float wl[IN_F * OUT_F];  // 16 KB
    int tid = threadIdx.x;
#pragma unroll
    for (int u = 0; u < 4; ++u) {
        int idx = (u * 256 + tid) * 4;
        *(float4*)&wl[idx] = *(const float4*)&w[idx];
    }
    __syncthreads();

    int gid = blockIdx.x * 256 + tid;
    int i  = gid >> 2;   // row 0..16383
    int ks = gid & 3;    // k quarter

    float acc[OUT_F];
#pragma unroll
    for (int j = 0; j < OUT_F; ++j) acc[j] = 0.f;

    const float* ip = inp + (size_t)i * IN_F + ks * 32;
#pragma unroll
    for (int kb = 0; kb < 8; ++kb) {
        float4 a4 = *(const float4*)(ip + kb * 4);
        float av[4] = {a4.x, a4.y, a4.z, a4.w};
#pragma unroll
        for (int kk = 0; kk < 4; ++kk) {
            int k = ks * 32 + kb * 4 + kk;
            const float* wr = &wl[k * OUT_F];
#pragma unroll
            for (int j4 = 0; j4 < 8; ++j4) {
                float4 w4 = *(const float4*)(wr + j4 * 4);
                acc[j4 * 4 + 0] = fmaf(av[kk], w4.x, acc[j4 * 4 + 0]);
                acc[j4 * 4 + 1] = fmaf(av[kk], w4.y, acc[j4 * 4 + 1]);
                acc[j4 * 4 + 2] = fmaf(av[kk], w4.z, acc[j4 * 4 + 2]);
                acc[j4 * 4 + 3] = fmaf(av[kk], w4.w, acc[j4 * 4 + 3]);
            }
        }
    }
#pragma unroll
    for (int j = 0; j < OUT_F; ++j) {
        acc[j] += __shfl_xor(acc[j], 1);
        acc[j] += __shfl_xor(acc[j], 2);
    }
#pragma unroll
    for (int jj = 0; jj < 8; ++jj) {
        int j = ks * 8 + jj;
        supB[(size_t)j * N + i] = f2bf(acc[j]);
    }
}

// Kernel B: out[row][j] += adj[rows, ksplit] @ sup[ksplit, j] via bf16 MFMA.
// WG = 32 rows x KR k-split. 4 waves = 2 M-tiles x 2 N-tiles (16x16 each).
// adj fp32 staged to LDS (global_load_lds, XOR-swizzled source), converted to
// bf16 in-register; B (supB) read as 16-B fragments straight from L2.
__global__ __launch_bounds__(256, 5) void gcn_aggregate(const float* __restrict__ adj,
                                                        const unsigned short* __restrict__ supB,
                                                        float* __restrict__ out) {
    __shared__ float sA[2][ROWS * KC];  // 2 x 16 KB, 16B-block-swizzled [row][k]

    int wg = blockIdx.x;
    int rb = wg >> 3;          // row block 0..511 (32 rows each)
    int sp = wg & 7;           // k split
    int tid  = threadIdx.x;
    int wv   = tid >> 6;
    int lane = tid & 63;
    int mt = wv >> 1;          // M-tile 0..1
    int nt = wv & 1;           // N-tile 0..1
    int lrow = lane & 15;      // row/col within tile
    int kgrp = lane >> 4;      // k-group 0..3 (8 k each)

    int rowblk = rb * ROWS;
    int kbase  = sp * KR;

    float4v acc = {0.f, 0.f, 0.f, 0.f};

    // Stage adj[rowblk..+32][kwin] fp32 -> LDS, 4 x dwordx4 per thread.
    // LDS dest is linear (wave base + lane*16B); the 16B-block k-position is
    // XOR-pre-swizzled on the GLOBAL side: linear slot f holds global block
    // (row = f>>5, kblk = (f&31) ^ (row&7)). Reads apply the same XOR.
    auto stage = [&](int buf, int c) {
#pragma unroll
        for (int u = 0; u < 4; ++u) {
            int f    = u * 256 + tid;            // 16B-block slot 0..1023
            int row  = f >> 5;                   // 32 blocks per row (KC=128)
            int gblk = (f & 31) ^ (row & 7);
            const float* gp = adj + (size_t)(rowblk + row) * N + kbase + c * KC + gblk * 4;
            float* lp = &sA[buf][(u * 256 + wv * 64) * 4];
            GLOAD_LDS16(gp, lp);
        }
    };

    int rowA = mt * 16 + lrow;      // A row this lane reads
    int sw   = rowA & 7;            // swizzle key
    const unsigned short* bprow = supB + (size_t)(nt * 16 + lrow) * N + kbase + kgrp * 8;

    stage(0, 0);
    __syncthreads();

    for (int c = 0; c < CHUNKS; ++c) {
        int cur = c & 1;
        if (c + 1 < CHUNKS) stage(cur ^ 1, c + 1);  // async, drained by end-of-iter sync

        // B fragments for this chunk (L2-resident, 16 B per window)
        const unsigned short* bp = bprow + c * KC;
        short8v b0 = *(const short8v*)(bp + 0);
        short8v b1 = *(const short8v*)(bp + 32);
        short8v b2 = *(const short8v*)(bp + 64);
        short8v b3 = *(const short8v*)(bp + 96);

#pragma unroll
        for (int w = 0; w < 4; ++w) {
            int kw   = w * 32;
            int blk0 = rowA * 32 + (kw >> 2) + kgrp * 2;   // 16B-block index
            float4 a0 = *(const float4*)&sA[cur][((blk0 ^ sw) << 2)];
            float4 a1 = *(const float4*)&sA[cur][(((blk0 + 1) ^ sw) << 2)];
            short8v af;
            af[0] = (short)f2bf(a0.x); af[1] = (short)f2bf(a0.y);
            af[2] = (short)f2bf(a0.z); af[3] = (short)f2bf(a0.w);
            af[4] = (short)f2bf(a1.x); af[5] = (short)f2bf(a1.y);
            af[6] = (short)f2bf(a1.z); af[7] = (short)f2bf(a1.w);
            short8v bf = (w == 0) ? b0 : (w == 1) ? b1 : (w == 2) ? b2 : b3;
            acc = __builtin_amdgcn_mfma_f32_16x16x32_bf16(af, bf, acc, 0, 0, 0);
        }
        __syncthreads();  // drains next-chunk DMA + fences buffer reuse
    }

    // C/D layout: col = lane&15, row = (lane>>4)*4 + reg  (m89-verified)
    int orow = rowblk + mt * 16 + kgrp * 4;
    int ocol = nt * 16 + lrow;
#pragma unroll
    for (int r = 0; r < 4; ++r)
        atomicAdd(&out[(size_t)(orow + r) * OUT_F + ocol], acc[r]);
}

__global__ __launch_bounds__(256) void gcn_relu(float* __restrict__ out) {
    int gid = blockIdx.x * 256 + threadIdx.x;  // 131072 float4s
    float4* p = (float4*)out;
    float4 v = p[gid];
    v.x = fmaxf(v.x, 0.f);
    v.y = fmaxf(v.y, 0.f);
    v.z = fmaxf(v.z, 0.f);
    v.w = fmaxf(v.w, 0.f);
    p[gid] = v;
}

extern "C" void kernel_launch(void* const* d_in, const int* in_sizes, int n_in,
                              void* d_out, int out_size, void* d_ws, size_t ws_size,
                              hipStream_t stream) {
    (void)in_sizes; (void)n_in; (void)out_size; (void)ws_size;
    const float* inp = (const float*)d_in[0];   // [16384,128]
    const float* adj = (const float*)d_in[1];   // [16384,16384]
    const float* wgt = (const float*)d_in[2];   // [128,32]
    float* out = (float*)d_out;                 // [16384,32]
    unsigned short* supB = (unsigned short*)d_ws;  // [32][16384] bf16 = 1 MB

    hipMemsetAsync(out, 0, (size_t)N * OUT_F * sizeof(float), stream);
    gcn_support<<<(N * 4) / 256, 256, 0, stream>>>(inp, wgt, supB);
    gcn_aggregate<<<(N / ROWS) * NSPLIT, 256, 0, stream>>>(adj, supB, out);
    gcn_relu<<<(N * OUT_F / 4) / 256, 256, 0, stream>>>(out);
}